// Round 11
// baseline (160.248 us; speedup 1.0000x reference)
//
#include <hip/hip_runtime.h>
#include <hip/hip_fp16.h>

#define DEV __device__ __forceinline__

typedef __bf16 bf16x8 __attribute__((ext_vector_type(8)));
typedef float f32x4 __attribute__((ext_vector_type(4)));
typedef short s16x8 __attribute__((ext_vector_type(8)));
typedef unsigned short u16;

static constexpr int D = 1024;
static constexpr int M = 16384;   // 8*2048 rows
static constexpr int R = 32;      // rows per block
static constexpr float EPS = 1e-8f;
static constexpr int PAD = 1028;  // half2 stride of stash rows

// LDS union: GEMM phase: A_lds [0, 64K). P2: stash [0,131584), red, stats.
static constexpr int SMEM_BYTES = 136192;
static constexpr int RED_OFF = 131584;
static constexpr int STATS_OFF = 135680;

DEV u16 f2bf(float f) {
  union { float f; unsigned u; } v; v.f = f;
  unsigned u = v.u;
  return (u16)((u + 0x7FFFu + ((u >> 16) & 1u)) >> 16);  // RNE
}

union H2x4 { s16x8 v; __half2 h[4]; };

// ---------------- prep: pm[k][n] f32 -> bt in GEMM-chunk fragment layout ----------------
// chunk ch = kk*2 + nh (32 KB): u16 addr = ch*16384 + (cb*64 + kg*16 + c15)*8 + je
// holds col = nh*512 + cb*16 + c15, k = kk*32 + kg*8 + je
__global__ __launch_bounds__(256) void k_prep(const float* __restrict__ pm,
                                              u16* __restrict__ bt) {
  __shared__ float t[32][33];
  int bx = blockIdx.x * 32, by = blockIdx.y * 32;
  int tx = threadIdx.x, ty = threadIdx.y;  // 32 x 8
#pragma unroll
  for (int j = 0; j < 32; j += 8)
    t[ty + j][tx] = pm[(size_t)(by + ty + j) * D + bx + tx];
  __syncthreads();
#pragma unroll
  for (int j = 0; j < 32; j += 8) {
    int col = bx + ty + j, k = by + tx;
    int kk = k >> 5, nh = col >> 9, cb = (col >> 4) & 31, c15 = col & 15;
    int kg = (k >> 3) & 3, je = k & 7;
    bt[(size_t)(kk * 2 + nh) * 16384 + (size_t)((cb * 64 + kg * 16 + c15) * 8 + je)] =
        f2bf(t[tx][ty + j]);
  }
}

// ---------------- fused: stage A + barrier-free GEMM (2-deep B ring) + coherence + rotate + LN ----------------
__global__ __launch_bounds__(512, 1) void k_fused(
    const float* __restrict__ xr, const float* __restrict__ xi,
    const u16* __restrict__ bt, const float* __restrict__ cfp,
    const float* __restrict__ lw, const float* __restrict__ lb,
    float* __restrict__ outR, float* __restrict__ outI) {
  __shared__ __align__(16) unsigned char smem[SMEM_BYTES];
  u16* A_lds = (u16*)smem;                    // 4096 units x 16B (GEMM phase)
  __half2* stash = (__half2*)smem;            // [32][PAD] (P2 phase)
  float* red = (float*)(smem + RED_OFF);      // [32][8][4]
  float* stats = (float*)(smem + STATS_OFF);  // [32][4]

  const int tid = threadIdx.x;
  const int lane = tid & 63;
  const int l15 = lane & 15, l4 = lane >> 4;
  const int wv = tid >> 6;  // 8 waves; wave wv owns cols {nh*512 + wv*64 .. +63}
  const size_t row0 = (size_t)blockIdx.x * R;
  const float cfv = cfp[0];

  // ---- phase 0: stage A panel (xr), f32 -> bf16, fragment-major + XOR swizzle ----
  {
    int row = tid >> 4;   // 0..31
    int s16 = tid & 15;
    const float* src = xr + (row0 + row) * D;
#pragma unroll
    for (int it = 0; it < 4; ++it)
#pragma unroll
      for (int h = 0; h < 2; ++h) {
        int kgl = it * 32 + s16 * 2 + h;  // 8-float group 0..127
        f32x4 a = *(const f32x4*)(src + kgl * 8);
        f32x4 b = *(const f32x4*)(src + kgl * 8 + 4);
        s16x8 v;
        v[0] = (short)f2bf(a.x); v[1] = (short)f2bf(a.y);
        v[2] = (short)f2bf(a.z); v[3] = (short)f2bf(a.w);
        v[4] = (short)f2bf(b.x); v[5] = (short)f2bf(b.y);
        v[6] = (short)f2bf(b.z); v[7] = (short)f2bf(b.w);
        int kk = kgl >> 2, kg = kgl & 3;
        int u = kk * 128 + (row >> 4) * 64 + kg * 16 + ((row & 15) ^ (kk & 15));
        *(s16x8*)&A_lds[u * 8] = v;
      }
  }
  __syncthreads();

  // ---- GEMM: barrier-free; A from LDS, B from L2 via 2-deep register ring ----
  f32x4 acc[2][8] = {};  // [rb][f], f = nh*4+nf

  auto loadA = [&](int kk, bf16x8 (&af)[2]) {
#pragma unroll
    for (int rb = 0; rb < 2; ++rb) {
      int u = kk * 128 + rb * 64 + l4 * 16 + (l15 ^ (kk & 15));
      af[rb] = __builtin_bit_cast(bf16x8, *(const s16x8*)&A_lds[u * 8]);
    }
  };
  auto loadB4 = [&](int s, bf16x8 (&b)[4]) {
    const u16* p = bt + (size_t)s * 16384 + (size_t)(wv * 4) * 512 + (size_t)lane * 8;
#pragma unroll
    for (int nf = 0; nf < 4; ++nf)
      b[nf] = __builtin_bit_cast(bf16x8, *(const s16x8*)(p + nf * 512));
  };
  auto step4 = [&](bf16x8 (&a)[2], bf16x8 (&b)[4], int nh) {
    __builtin_amdgcn_s_setprio(1);
#pragma unroll
    for (int nf = 0; nf < 4; ++nf) {
      acc[0][nh * 4 + nf] =
          __builtin_amdgcn_mfma_f32_16x16x32_bf16(a[0], b[nf], acc[0][nh * 4 + nf], 0, 0, 0);
      acc[1][nh * 4 + nf] =
          __builtin_amdgcn_mfma_f32_16x16x32_bf16(a[1], b[nf], acc[1][nh * 4 + nf], 0, 0, 0);
    }
    __builtin_amdgcn_s_setprio(0);
  };

  {
    bf16x8 a[2], b0v[4], b1v[4];
    loadB4(0, b0v);
    loadB4(1, b1v);
    for (int kk = 0; kk < 32; ++kk) {
      loadA(kk, a);
      step4(a, b0v, 0);
      if (kk < 31) loadB4(2 * kk + 2, b0v);
      step4(a, b1v, 1);
      if (kk < 31) loadB4(2 * kk + 3, b1v);
    }
  }
  __syncthreads();  // GEMM done; repurpose LDS as stash

  // ---- P2a: read (a,b) once (L3-hot), coherence partials, stash f16 ----
  float sc8[8], ss8[8];
#pragma unroll
  for (int p = 0; p < 8; ++p) { sc8[p] = 0.f; ss8[p] = 0.f; }
#pragma unroll
  for (int rb = 0; rb < 2; ++rb)
#pragma unroll
    for (int i = 0; i < 4; ++i) {
      const int p = rb * 4 + i;
      const int row_l = rb * 16 + l4 * 4 + i;
      const float* ar = xr + (row0 + row_l) * D;
      const float* ai = xi + (row0 + row_l) * D;
#pragma unroll
      for (int q = 0; q < 8; ++q) {
        int col = (q >> 2) * 512 + wv * 64 + (q & 3) * 16 + l15;
        float a = ar[col], b = ai[col];
        float xe = a + EPS, ye = b + EPS;
        float inv = rsqrtf(xe * xe + ye * ye);
        sc8[p] += xe * inv;
        ss8[p] += ye * inv;
        stash[row_l * PAD + col] = __floats2half2_rn(a, b);
      }
    }
#pragma unroll
  for (int p = 0; p < 8; ++p)
#pragma unroll
    for (int d = 1; d < 16; d <<= 1) {
      sc8[p] += __shfl_xor(sc8[p], d, 64);
      ss8[p] += __shfl_xor(ss8[p], d, 64);
    }
  if (l15 == 0) {
#pragma unroll
    for (int rb = 0; rb < 2; ++rb)
#pragma unroll
      for (int i = 0; i < 4; ++i) {
        int p = rb * 4 + i, row_l = rb * 16 + l4 * 4 + i;
        red[(row_l * 8 + wv) * 4 + 0] = sc8[p];
        red[(row_l * 8 + wv) * 4 + 1] = ss8[p];
      }
  }
  __syncthreads();
  float srow[8];
#pragma unroll
  for (int rb = 0; rb < 2; ++rb)
#pragma unroll
    for (int i = 0; i < 4; ++i) {
      int p = rb * 4 + i, row_l = rb * 16 + l4 * 4 + i;
      float tsc = 0.f, tss = 0.f;
#pragma unroll
      for (int w8 = 0; w8 < 8; ++w8) {
        tsc += red[(row_l * 8 + w8) * 4 + 0];
        tss += red[(row_l * 8 + w8) * 4 + 1];
      }
      float coh = (tsc * tsc + tss * tss) * (1.0f / (1024.0f * 1024.0f));
      srow[p] = cfv * (1.0f - coh);
    }
  __syncthreads();  // red reuse barrier

  // ---- P2b: rotate + normalize (poly sincos, |t| small), LN partials ----
  float snr[8], sqr[8], sni[8], sqi[8];
#pragma unroll
  for (int p = 0; p < 8; ++p) { snr[p] = 0.f; sqr[p] = 0.f; sni[p] = 0.f; sqi[p] = 0.f; }
#pragma unroll
  for (int rb = 0; rb < 2; ++rb)
#pragma unroll
    for (int i = 0; i < 4; ++i) {
      const int p = rb * 4 + i;
      const int row_l = rb * 16 + l4 * 4 + i;
      const float sr = srow[p];
#pragma unroll
      for (int q = 0; q < 8; ++q) {
        int col = (q >> 2) * 512 + wv * 64 + (q & 3) * 16 + l15;
        float t = acc[rb][q][i] * sr;
        float t2 = t * t;
        float sn = t * (1.f + t2 * (-1.f / 6.f + t2 * (1.f / 120.f - t2 * (1.f / 5040.f))));
        float cs = 1.f + t2 * (-0.5f + t2 * (1.f / 24.f - t2 * (1.f / 720.f)));
        __half2 ab = stash[row_l * PAD + col];
        float a = __low2float(ab), b = __high2float(ab);
        float nr = a * cs - b * sn;
        float ni = a * sn + b * cs;
        float inv = rsqrtf(nr * nr + ni * ni + EPS);
        nr *= inv; ni *= inv;
        stash[row_l * PAD + col] = __floats2half2_rn(nr, ni);
        snr[p] += nr; sqr[p] += nr * nr;
        sni[p] += ni; sqi[p] += ni * ni;
      }
    }
#pragma unroll
  for (int p = 0; p < 8; ++p)
#pragma unroll
    for (int d = 1; d < 16; d <<= 1) {
      snr[p] += __shfl_xor(snr[p], d, 64);
      sqr[p] += __shfl_xor(sqr[p], d, 64);
      sni[p] += __shfl_xor(sni[p], d, 64);
      sqi[p] += __shfl_xor(sqi[p], d, 64);
    }
  if (l15 == 0) {
#pragma unroll
    for (int rb = 0; rb < 2; ++rb)
#pragma unroll
      for (int i = 0; i < 4; ++i) {
        int p = rb * 4 + i, row_l = rb * 16 + l4 * 4 + i;
        red[(row_l * 8 + wv) * 4 + 0] = snr[p];
        red[(row_l * 8 + wv) * 4 + 1] = sqr[p];
        red[(row_l * 8 + wv) * 4 + 2] = sni[p];
        red[(row_l * 8 + wv) * 4 + 3] = sqi[p];
      }
  }
  __syncthreads();
  if (wv == 0 && l15 == 0) {
#pragma unroll
    for (int rb = 0; rb < 2; ++rb)
#pragma unroll
      for (int i = 0; i < 4; ++i) {
        int row_l = rb * 16 + l4 * 4 + i;
        float s0 = 0.f, s1 = 0.f, s2 = 0.f, s3 = 0.f;
#pragma unroll
        for (int w8 = 0; w8 < 8; ++w8) {
          s0 += red[(row_l * 8 + w8) * 4 + 0];
          s1 += red[(row_l * 8 + w8) * 4 + 1];
          s2 += red[(row_l * 8 + w8) * 4 + 2];
          s3 += red[(row_l * 8 + w8) * 4 + 3];
        }
        float mu_r = s0 * (1.f / 1024.f);
        float mu_i = s2 * (1.f / 1024.f);
        stats[row_l * 4 + 0] = mu_r;
        stats[row_l * 4 + 1] = rsqrtf(s1 * (1.f / 1024.f) - mu_r * mu_r + EPS);
        stats[row_l * 4 + 2] = mu_i;
        stats[row_l * 4 + 3] = rsqrtf(s3 * (1.f / 1024.f) - mu_i * mu_i + EPS);
      }
  }
  __syncthreads();

  // ---- P2c: apply LN, coalesced f32x4 writes of both outputs ----
  {
    int row = tid >> 4, cg = tid & 15;
    float mu_r = stats[row * 4 + 0], rd_r = stats[row * 4 + 1];
    float mu_i = stats[row * 4 + 2], rd_i = stats[row * 4 + 3];
    float* orp = outR + (row0 + row) * D;
    float* oip = outI + (row0 + row) * D;
#pragma unroll
    for (int v = 0; v < 16; ++v) {
      int col = v * 64 + cg * 4;
      H2x4 hv;
      hv.v = *(const s16x8*)&stash[row * PAD + col];
      f32x4 w4 = *(const f32x4*)(lw + col);
      f32x4 b4 = *(const f32x4*)(lb + col);
      f32x4 o_r, o_i;
#pragma unroll
      for (int j = 0; j < 4; ++j) {
        float nr = __low2float(hv.h[j]), ni = __high2float(hv.h[j]);
        o_r[j] = (nr - mu_r) * rd_r * w4[j] + b4[j];
        o_i[j] = (ni - mu_i) * rd_i * w4[j] + b4[j];
      }
      *(f32x4*)(orp + col) = o_r;
      *(f32x4*)(oip + col) = o_i;
    }
  }
}

extern "C" void kernel_launch(void* const* d_in, const int* in_sizes, int n_in,
                              void* d_out, int out_size, void* d_ws, size_t ws_size,
                              hipStream_t stream) {
  const float* xr = (const float*)d_in[0];
  const float* xi = (const float*)d_in[1];
  const float* pm = (const float*)d_in[2];
  const float* cf = (const float*)d_in[3];
  const float* lw = (const float*)d_in[4];
  const float* lb = (const float*)d_in[5];
  float* outR = (float*)d_out;
  float* outI = outR + (size_t)M * D;
  u16* bt = (u16*)d_ws;  // 2 MB, GEMM-chunk layout

  k_prep<<<dim3(32, 32), dim3(32, 8), 0, stream>>>(pm, bt);
  k_fused<<<M / R, 512, 0, stream>>>(xr, xi, bt, cf, lw, lb, outR, outI);
}

// Round 12
// 150.294 us; speedup vs baseline: 1.0662x; 1.0662x over previous
//
#include <hip/hip_runtime.h>
#include <hip/hip_fp16.h>

#define DEV __device__ __forceinline__

typedef __bf16 bf16x8 __attribute__((ext_vector_type(8)));
typedef float f32x4 __attribute__((ext_vector_type(4)));
typedef short s16x8 __attribute__((ext_vector_type(8)));
typedef unsigned short u16;

static constexpr int D = 1024;
static constexpr int M = 16384;   // 8*2048 rows
static constexpr int R = 16;      // rows per block
static constexpr float EPS = 1e-8f;

// LDS (bytes): A [0,32K) | B [32K,64K)  -> P2 stash half2[16][1024] over A∪B
// red @65536 (16*8*4 f32) | stats @67584 (16*4) | scale @67840 (16)
static constexpr int B_OFF = 32768;
static constexpr int RED_OFF = 65536;
static constexpr int STATS_OFF = 67584;
static constexpr int SCALE_OFF = 67840;
static constexpr int SMEM_BYTES = 67904;   // ~66.3 KB -> 2 blocks/CU

DEV u16 f2bf(float f) {
  union { float f; unsigned u; } v; v.f = f;
  unsigned u = v.u;
  return (u16)((u + 0x7FFFu + ((u >> 16) & 1u)) >> 16);  // RNE
}

DEV void async_copy16(const void* g, void* l) {
  __builtin_amdgcn_global_load_lds(
      (const __attribute__((address_space(1))) void*)g,
      (__attribute__((address_space(3))) void*)l, 16, 0, 0);
}

union H2x4 { s16x8 v; __half2 h[4]; };

// ---------------- prep: pm[k][n] f32 -> bt in GEMM-chunk fragment layout ----------------
// chunk ch = kk*2 + nh (32 KB): u16 addr = ch*16384 + (cb*64 + kg*16 + c15)*8 + je
// holds col = nh*512 + cb*16 + c15, k = kk*32 + kg*8 + je
__global__ __launch_bounds__(256) void k_prep(const float* __restrict__ pm,
                                              u16* __restrict__ bt) {
  __shared__ float t[32][33];
  int bx = blockIdx.x * 32, by = blockIdx.y * 32;
  int tx = threadIdx.x, ty = threadIdx.y;  // 32 x 8
#pragma unroll
  for (int j = 0; j < 32; j += 8)
    t[ty + j][tx] = pm[(size_t)(by + ty + j) * D + bx + tx];
  __syncthreads();
#pragma unroll
  for (int j = 0; j < 32; j += 8) {
    int col = bx + ty + j, k = by + tx;
    int kk = k >> 5, nh = col >> 9, cb = (col >> 4) & 31, c15 = col & 15;
    int kg = (k >> 3) & 3, je = k & 7;
    bt[(size_t)(kk * 2 + nh) * 16384 + (size_t)((cb * 64 + kg * 16 + c15) * 8 + je)] =
        f2bf(t[tx][ty + j]);
  }
}

// ---------------- fused: P0(read+stage A+coherence) + GEMM + rotate/stash + LN ----------------
__global__ __launch_bounds__(512, 4) void k_fused(
    const float* __restrict__ xr, const float* __restrict__ xi,
    const u16* __restrict__ bt, const float* __restrict__ cfp,
    const float* __restrict__ lw, const float* __restrict__ lb,
    float* __restrict__ outR, float* __restrict__ outI) {
  __shared__ __align__(16) unsigned char smem[SMEM_BYTES];
  u16* A_lds = (u16*)smem;                      // 2048 units x 16B
  u16* B_u16 = (u16*)(smem + B_OFF);            // 2048 units x 16B (one 32KB chunk)
  __half2* stash = (__half2*)smem;              // [16][1024] (P2, over A∪B)
  float* red = (float*)(smem + RED_OFF);        // [16][8][4]
  float* stats = (float*)(smem + STATS_OFF);    // [16][4]
  float* scale_s = (float*)(smem + SCALE_OFF);  // [16]

  const int tid = threadIdx.x;
  const int lane = tid & 63;
  const int l15 = lane & 15, l4 = lane >> 4;
  const int wv = tid >> 6;  // 8 waves; wave wv owns cols {nh*512 + wv*64 .. +63}
  const size_t row0 = (size_t)blockIdx.x * R;
  const float cfv = cfp[0];

  // ---- P0: read xr+xi once, stage A (bf16 frag, XOR row swizzle), coherence ----
  {
    int row = tid >> 5;  // 0..15, 32 threads per row (contiguous lanes)
    int s32 = tid & 31;
    const float* xrp = xr + (row0 + row) * D;
    const float* xip = xi + (row0 + row) * D;
    float sc = 0.f, ss = 0.f;
#pragma unroll
    for (int it = 0; it < 4; ++it) {
      int kgl = it * 32 + s32;  // 8-float group 0..127
      f32x4 a0 = *(const f32x4*)(xrp + kgl * 8);
      f32x4 a1 = *(const f32x4*)(xrp + kgl * 8 + 4);
      f32x4 b0 = *(const f32x4*)(xip + kgl * 8);
      f32x4 b1 = *(const f32x4*)(xip + kgl * 8 + 4);
      float fx[8] = {a0.x, a0.y, a0.z, a0.w, a1.x, a1.y, a1.z, a1.w};
      float fy[8] = {b0.x, b0.y, b0.z, b0.w, b1.x, b1.y, b1.z, b1.w};
      s16x8 v;
#pragma unroll
      for (int j = 0; j < 8; ++j) {
        float x = fx[j] + EPS, y = fy[j] + EPS;
        float inv = rsqrtf(x * x + y * y);
        sc += x * inv;
        ss += y * inv;
        v[j] = (short)f2bf(fx[j]);
      }
      int kk = kgl >> 2, kg = kgl & 3;
      int u = kk * 64 + kg * 16 + (row ^ (kk & 15));
      *(s16x8*)&A_lds[u * 8] = v;
    }
    sc += __shfl_xor(sc, 1, 64); sc += __shfl_xor(sc, 2, 64);
    sc += __shfl_xor(sc, 4, 64); sc += __shfl_xor(sc, 8, 64);
    sc += __shfl_xor(sc, 16, 64);
    ss += __shfl_xor(ss, 1, 64); ss += __shfl_xor(ss, 2, 64);
    ss += __shfl_xor(ss, 4, 64); ss += __shfl_xor(ss, 8, 64);
    ss += __shfl_xor(ss, 16, 64);
    if (s32 == 0) {
      float coh = (sc * sc + ss * ss) * (1.0f / (1024.0f * 1024.0f));
      scale_s[row] = cfv * (1.0f - coh);
    }
  }
  __syncthreads();

  // ---- GEMM: 64 substeps (kk x nh), single 32KB B buffer via global_load_lds ----
  f32x4 acc[8] = {};  // [f], f = nh*4+nf; col(f) = (f>>2)*512 + wv*64 + (f&3)*16 + l15

  for (int kk = 0; kk < 32; ++kk) {
    int ua = kk * 64 + l4 * 16 + (l15 ^ (kk & 15));
    bf16x8 af = __builtin_bit_cast(bf16x8, *(const s16x8*)&A_lds[ua * 8]);
#pragma unroll
    for (int nh = 0; nh < 2; ++nh) {
      const u16* src = bt + (size_t)(kk * 2 + nh) * 16384;
#pragma unroll
      for (int r = 0; r < 4; ++r) {
        int off = (r * 8 + wv) * 512 + lane * 8;
        async_copy16(src + off, B_u16 + off);
      }
      __syncthreads();  // drains vmcnt (gl_lds) + barrier: B chunk ready
      __builtin_amdgcn_s_setprio(1);
#pragma unroll
      for (int nf = 0; nf < 4; ++nf) {
        int ub = (wv * 4 + nf) * 64 + l4 * 16 + l15;
        bf16x8 bf = __builtin_bit_cast(bf16x8, *(const s16x8*)&B_u16[ub * 8]);
        acc[nh * 4 + nf] =
            __builtin_amdgcn_mfma_f32_16x16x32_bf16(af, bf, acc[nh * 4 + nf], 0, 0, 0);
      }
      __builtin_amdgcn_s_setprio(0);
      __syncthreads();  // all waves done reading B before next stage overwrites
    }
  }

  // ---- P2a: rotate + normalize once (a,b from global, L3-hot); stash half2 in LDS;
  //           LN partial sums. acc is READ-ONLY (r10 constraint). ----
  float srow4[4];
#pragma unroll
  for (int i = 0; i < 4; ++i) srow4[i] = scale_s[l4 * 4 + i];

  float s_r[4], q_r[4], s_i[4], q_i[4];
#pragma unroll
  for (int i = 0; i < 4; ++i) { s_r[i] = 0.f; q_r[i] = 0.f; s_i[i] = 0.f; q_i[i] = 0.f; }
#pragma unroll
  for (int i = 0; i < 4; ++i) {
    const int row_l = l4 * 4 + i;
    const float scl = srow4[i];
    const float* ar = xr + (row0 + row_l) * D;
    const float* ai = xi + (row0 + row_l) * D;
#pragma unroll
    for (int q = 0; q < 8; ++q) {
      int col = (q >> 2) * 512 + wv * 64 + (q & 3) * 16 + l15;
      float a = ar[col], b = ai[col];
      float t = acc[q][i] * scl;
      float t2 = t * t;
      float sn = t * (1.f + t2 * (-1.f / 6.f + t2 * (1.f / 120.f - t2 * (1.f / 5040.f))));
      float cs = 1.f + t2 * (-0.5f + t2 * (1.f / 24.f - t2 * (1.f / 720.f)));
      float nr = a * cs - b * sn;
      float ni = a * sn + b * cs;
      float inv = rsqrtf(nr * nr + ni * ni + EPS);
      nr *= inv; ni *= inv;
      int colx = col ^ ((row_l & 3) << 4);  // bank swizzle, bijective per row
      stash[row_l * 1024 + colx] = __floats2half2_rn(nr, ni);
      s_r[i] += nr; q_r[i] += nr * nr;
      s_i[i] += ni; q_i[i] += ni * ni;
    }
  }
#pragma unroll
  for (int i = 0; i < 4; ++i)
#pragma unroll
    for (int d = 1; d < 16; d <<= 1) {
      s_r[i] += __shfl_xor(s_r[i], d, 64);
      q_r[i] += __shfl_xor(q_r[i], d, 64);
      s_i[i] += __shfl_xor(s_i[i], d, 64);
      q_i[i] += __shfl_xor(q_i[i], d, 64);
    }
  if (l15 == 0) {
#pragma unroll
    for (int i = 0; i < 4; ++i) {
      int row_l = l4 * 4 + i;
      red[(row_l * 8 + wv) * 4 + 0] = s_r[i];
      red[(row_l * 8 + wv) * 4 + 1] = q_r[i];
      red[(row_l * 8 + wv) * 4 + 2] = s_i[i];
      red[(row_l * 8 + wv) * 4 + 3] = q_i[i];
    }
  }
  __syncthreads();
  if (wv == 0 && l15 == 0) {
#pragma unroll
    for (int i = 0; i < 4; ++i) {
      int row_l = l4 * 4 + i;
      float s0 = 0.f, s1 = 0.f, s2 = 0.f, s3 = 0.f;
#pragma unroll
      for (int w8 = 0; w8 < 8; ++w8) {
        s0 += red[(row_l * 8 + w8) * 4 + 0];
        s1 += red[(row_l * 8 + w8) * 4 + 1];
        s2 += red[(row_l * 8 + w8) * 4 + 2];
        s3 += red[(row_l * 8 + w8) * 4 + 3];
      }
      float mu_r = s0 * (1.f / 1024.f);
      float mu_i = s2 * (1.f / 1024.f);
      stats[row_l * 4 + 0] = mu_r;
      stats[row_l * 4 + 1] = rsqrtf(s1 * (1.f / 1024.f) - mu_r * mu_r + EPS);
      stats[row_l * 4 + 2] = mu_i;
      stats[row_l * 4 + 3] = rsqrtf(s3 * (1.f / 1024.f) - mu_i * mu_i + EPS);
    }
  }
  __syncthreads();

  // ---- P2c: apply LN from stash, coalesced f32x4 writes of both outputs ----
  {
    int row = tid >> 5, cg = tid & 31;  // 32 threads per row
    float mu_r = stats[row * 4 + 0], rd_r = stats[row * 4 + 1];
    float mu_i = stats[row * 4 + 2], rd_i = stats[row * 4 + 3];
    float* orp = outR + (row0 + row) * D;
    float* oip = outI + (row0 + row) * D;
#pragma unroll
    for (int v = 0; v < 8; ++v) {
      int col = v * 128 + cg * 4;
      int colx = col ^ ((row & 3) << 4);  // 4 consecutive cols stay contiguous
      H2x4 hv;
      hv.v = *(const s16x8*)&stash[row * 1024 + colx];
      f32x4 w4 = *(const f32x4*)(lw + col);
      f32x4 b4 = *(const f32x4*)(lb + col);
      f32x4 o_r, o_i;
#pragma unroll
      for (int j = 0; j < 4; ++j) {
        float nr = __low2float(hv.h[j]), ni = __high2float(hv.h[j]);
        o_r[j] = (nr - mu_r) * rd_r * w4[j] + b4[j];
        o_i[j] = (ni - mu_i) * rd_i * w4[j] + b4[j];
      }
      *(f32x4*)(orp + col) = o_r;
      *(f32x4*)(oip + col) = o_i;
    }
  }
}

extern "C" void kernel_launch(void* const* d_in, const int* in_sizes, int n_in,
                              void* d_out, int out_size, void* d_ws, size_t ws_size,
                              hipStream_t stream) {
  const float* xr = (const float*)d_in[0];
  const float* xi = (const float*)d_in[1];
  const float* pm = (const float*)d_in[2];
  const float* cf = (const float*)d_in[3];
  const float* lw = (const float*)d_in[4];
  const float* lb = (const float*)d_in[5];
  float* outR = (float*)d_out;
  float* outI = outR + (size_t)M * D;
  u16* bt = (u16*)d_ws;  // 2 MB, GEMM-chunk layout

  k_prep<<<dim3(32, 32), dim3(32, 8), 0, stream>>>(pm, bt);
  k_fused<<<M / R, 512, 0, stream>>>(xr, xi, bt, cf, lw, lb, outR, outI);
}